// Round 2
// baseline (722.464 us; speedup 1.0000x reference)
//
#include <hip/hip_runtime.h>

// All-pole time-varying IIR via chunked affine-state decomposition.
// y[t] = K[t]*x[t] - sum_m A[t][m]*y[t-1-m], coeffs lin-interp per 80-sample frame.
// C=100 chunks of L=160 (2 frames). Phase1: 31 lane-runs/chunk build affine map (M_c, f_c).
// Phase2: per-batch scan s <- M_c s + f_c (depth-4 register prefetch).
// Phase3: exact re-run per chunk from known start state.
// Inner loops use: (a) two-accumulator trick to fold coefficient interpolation
// (y = inp - acc_c0 - f*acc_dc), (b) 40-deep linear history window with 10-step
// static unroll to eliminate the 30-mov/step history shift.

#define Bb 64
#define Tt 16000
#define Nn 200
#define Pp 80
#define Mm 30
#define Dd 31
#define Cc 100
#define Ll 160

#define MF_FLOATS ((size_t)Bb * Cc * 31 * Mm)
#define SS_FLOATS ((size_t)Bb * Cc * Mm)

__device__ __forceinline__ void load_coeffs(const float* __restrict__ p0,
                                            const float* __restrict__ p1,
                                            float (&c0)[Mm], float (&dc)[Mm],
                                            float& K0, float& dK) {
  K0 = p0[0];
  dK = p1[0] - K0;
#pragma unroll
  for (int m = 0; m < Mm; ++m) {
    float v0 = p0[m + 1];
    c0[m] = v0;
    dc[m] = p1[m + 1] - v0;
  }
}

// ---------------- Phase 1: per-chunk transition matrices ----------------
__global__ __launch_bounds__(256, 3) void phase1(const float* __restrict__ x,
                                                 const float* __restrict__ a,
                                                 float* __restrict__ Mf) {
  const int tid = threadIdx.x;
  const int wave = tid >> 6, lane = tid & 63, half = lane >> 5, role = lane & 31;
  const int ch = ((blockIdx.x * 4 + wave) << 1) + half;
  const int b = ch / Cc, c = ch % Cc;

  float hh[40];
#pragma unroll
  for (int i = 0; i < 40; ++i) hh[i] = 0.f;
  if (role < Mm) hh[29 - role] = 1.f;  // hh[29-m] = y[t-1-m]
  const float gmask = (role == 30) ? 1.f : 0.f;

  const float* abase = a + ((size_t)b * Nn + 2 * c) * Dd;
  float c0[Mm], dc[Mm], K0, dK;
  load_coeffs(abase, abase + Dd, c0, dc, K0, dK);  // frame 2c -> 2c+1 (always valid)

  const float* xp = x + (size_t)b * Tt + c * Ll;
  const float finc = 1.0f / Pp;
  float fbase = 0.f;

#pragma unroll 1
  for (int blk = 0; blk < 16; ++blk) {
    if (blk == 8) {
      const int n = 2 * c + 1;
      const float* p0 = a + ((size_t)b * Nn + n) * Dd;
      const float* p1 = (n + 1 < Nn) ? (p0 + Dd) : p0;
      load_coeffs(p0, p1, c0, dc, K0, dK);
      fbase = 0.f;
    }
    float xv[10];
    {
      const float2* x2 = reinterpret_cast<const float2*>(xp + blk * 10);
#pragma unroll
      for (int j = 0; j < 5; ++j) {
        float2 v = x2[j];
        xv[2 * j] = v.x;
        xv[2 * j + 1] = v.y;
      }
    }
#pragma unroll
    for (int k = 0; k < 10; ++k) {
      float a0 = 0.f, a1 = 0.f, d0 = 0.f, d1 = 0.f;
#pragma unroll
      for (int m = 0; m < Mm; m += 2) {
        float h0 = hh[29 + k - m];
        float h1 = hh[28 + k - m];
        a0 = fmaf(c0[m], h0, a0);
        d0 = fmaf(dc[m], h0, d0);
        a1 = fmaf(c0[m + 1], h1, a1);
        d1 = fmaf(dc[m + 1], h1, d1);
      }
      const float f = fmaf((float)k, finc, fbase);
      const float Kt = fmaf(dK, f, K0);
      const float inp = gmask * (Kt * xv[k]);
      const float y = fmaf(-f, d0 + d1, inp - (a0 + a1));
      hh[30 + k] = y;
    }
#pragma unroll
    for (int i = 0; i < 30; ++i) hh[i] = hh[i + 10];
    fbase += 10.0f * finc;  // 0.125 exact
  }

  if (role <= 30) {
    float* dst = Mf + ((size_t)ch * 31 + role) * Mm;
#pragma unroll
    for (int m = 0; m < Mm; ++m) dst[m] = hh[29 - m];
  }
}

// ---------------- Phase 2: sequential scan of chunk states ----------------
__device__ __forceinline__ void p2_load(const float* __restrict__ Mf, int ch, int lane,
                                        float (&R)[Dd]) {
  const float* nb = Mf + (size_t)ch * (31 * Mm);
  if (lane < Mm) {
#pragma unroll
    for (int j = 0; j < Dd; ++j) R[j] = nb[j * Mm + lane];  // R[j]=M[lane][j], R[30]=f[lane]
  }
}

__device__ __forceinline__ float p2_step(float s, const float (&R)[Dd]) {
  float a0 = R[Mm], a1 = 0.f;
#pragma unroll
  for (int j = 0; j < Mm; j += 2) {
    a0 = fmaf(R[j], __shfl(s, j, 64), a0);
    a1 = fmaf(R[j + 1], __shfl(s, j + 1, 64), a1);
  }
  return a0 + a1;
}

__global__ __launch_bounds__(64, 1) void phase2(const float* __restrict__ Mf,
                                                float* __restrict__ Sstart) {
  const int b = blockIdx.x, lane = threadIdx.x;
  const int chbase = b * Cc;
  float s = 0.f;
  float B0[Dd], B1[Dd], B2[Dd], B3[Dd];
  p2_load(Mf, chbase + 0, lane, B0);
  p2_load(Mf, chbase + 1, lane, B1);
  p2_load(Mf, chbase + 2, lane, B2);
  p2_load(Mf, chbase + 3, lane, B3);
#pragma unroll 1
  for (int c = 0; c < Cc; c += 4) {
    if (lane < Mm) Sstart[(size_t)(chbase + c) * Mm + lane] = s;
    s = p2_step(s, B0);
    if (c + 4 < Cc) p2_load(Mf, chbase + c + 4, lane, B0);
    if (lane < Mm) Sstart[(size_t)(chbase + c + 1) * Mm + lane] = s;
    s = p2_step(s, B1);
    if (c + 5 < Cc) p2_load(Mf, chbase + c + 5, lane, B1);
    if (lane < Mm) Sstart[(size_t)(chbase + c + 2) * Mm + lane] = s;
    s = p2_step(s, B2);
    if (c + 6 < Cc) p2_load(Mf, chbase + c + 6, lane, B2);
    if (lane < Mm) Sstart[(size_t)(chbase + c + 3) * Mm + lane] = s;
    s = p2_step(s, B3);
    if (c + 7 < Cc) p2_load(Mf, chbase + c + 7, lane, B3);
  }
}

// ---------------- Phase 3: exact re-run per chunk, one chunk per lane ----------------
__global__ __launch_bounds__(128, 1) void phase3(const float* __restrict__ x,
                                                 const float* __restrict__ a,
                                                 const float* __restrict__ Sstart,
                                                 float* __restrict__ out) {
  const int ch = blockIdx.x * 128 + threadIdx.x;  // 50 blocks * 128 = 6400 exactly
  const int b = ch / Cc, c = ch % Cc;

  float hh[40];
  const float* sp = Sstart + (size_t)ch * Mm;
#pragma unroll
  for (int m = 0; m < Mm; ++m) hh[29 - m] = sp[m];
#pragma unroll
  for (int i = 30; i < 40; ++i) hh[i] = 0.f;

  const float* abase = a + ((size_t)b * Nn + 2 * c) * Dd;
  float c0[Mm], dc[Mm], K0, dK;
  load_coeffs(abase, abase + Dd, c0, dc, K0, dK);

  const float* xp = x + (size_t)b * Tt + c * Ll;
  float* yp = out + (size_t)b * Tt + c * Ll;
  const float finc = 1.0f / Pp;
  float fbase = 0.f;

#pragma unroll 1
  for (int blk = 0; blk < 16; ++blk) {
    if (blk == 8) {
      const int n = 2 * c + 1;
      const float* p0 = a + ((size_t)b * Nn + n) * Dd;
      const float* p1 = (n + 1 < Nn) ? (p0 + Dd) : p0;
      load_coeffs(p0, p1, c0, dc, K0, dK);
      fbase = 0.f;
    }
    float xv[10];
    {
      const float2* x2 = reinterpret_cast<const float2*>(xp + blk * 10);
#pragma unroll
      for (int j = 0; j < 5; ++j) {
        float2 v = x2[j];
        xv[2 * j] = v.x;
        xv[2 * j + 1] = v.y;
      }
    }
    float yv[10];
#pragma unroll
    for (int k = 0; k < 10; ++k) {
      float a0 = 0.f, a1 = 0.f, d0 = 0.f, d1 = 0.f;
#pragma unroll
      for (int m = 0; m < Mm; m += 2) {
        float h0 = hh[29 + k - m];
        float h1 = hh[28 + k - m];
        a0 = fmaf(c0[m], h0, a0);
        d0 = fmaf(dc[m], h0, d0);
        a1 = fmaf(c0[m + 1], h1, a1);
        d1 = fmaf(dc[m + 1], h1, d1);
      }
      const float f = fmaf((float)k, finc, fbase);
      const float Kt = fmaf(dK, f, K0);
      const float y = fmaf(-f, d0 + d1, fmaf(Kt, xv[k], -(a0 + a1)));
      yv[k] = y;
      hh[30 + k] = y;
    }
    {
      float2* y2 = reinterpret_cast<float2*>(yp + blk * 10);
#pragma unroll
      for (int j = 0; j < 5; ++j) y2[j] = make_float2(yv[2 * j], yv[2 * j + 1]);
    }
#pragma unroll
    for (int i = 0; i < 30; ++i) hh[i] = hh[i + 10];
    fbase += 10.0f * finc;
  }
}

// ---------------- Fallback: serial, one lane per batch ----------------
__global__ void naive_kernel(const float* __restrict__ x, const float* __restrict__ a,
                             float* __restrict__ out) {
  const int b = blockIdx.x * blockDim.x + threadIdx.x;
  if (b >= Bb) return;
  float h[Mm];
#pragma unroll
  for (int m = 0; m < Mm; ++m) h[m] = 0.f;
  for (int n = 0; n < Nn; ++n) {
    const float* p0 = a + ((size_t)b * Nn + n) * Dd;
    const float* p1 = a + ((size_t)b * Nn + min(n + 1, Nn - 1)) * Dd;
    float c0[Mm], dc[Mm];
#pragma unroll
    for (int m = 0; m < Mm; ++m) {
      float v0 = p0[m + 1];
      c0[m] = v0;
      dc[m] = p1[m + 1] - v0;
    }
    const float K0 = p0[0], dK = p1[0] - K0;
    const float* xp = x + (size_t)b * Tt + n * Pp;
    float* yp = out + (size_t)b * Tt + n * Pp;
    for (int i = 0; i < Pp; ++i) {
      const float f = (float)i * (1.0f / Pp);
      float acc = 0.f;
#pragma unroll
      for (int m = 0; m < Mm; ++m) acc = fmaf(fmaf(dc[m], f, c0[m]), h[m], acc);
      const float y = fmaf(fmaf(dK, f, K0), xp[i], -acc);
      yp[i] = y;
#pragma unroll
      for (int m = Mm - 1; m > 0; --m) h[m] = h[m - 1];
      h[0] = y;
    }
  }
}

extern "C" void kernel_launch(void* const* d_in, const int* in_sizes, int n_in,
                              void* d_out, int out_size, void* d_ws, size_t ws_size,
                              hipStream_t stream) {
  const float* x = (const float*)d_in[0];  // (64, 16000) f32
  const float* a = (const float*)d_in[1];  // (64, 200, 31) f32
  float* out = (float*)d_out;              // (64, 16000) f32

  const size_t need = (MF_FLOATS + SS_FLOATS) * sizeof(float);
  if (ws_size < need) {
    naive_kernel<<<1, 64, 0, stream>>>(x, a, out);
    return;
  }
  float* Mf = (float*)d_ws;
  float* Sstart = Mf + MF_FLOATS;

  phase1<<<800, 256, 0, stream>>>(x, a, Mf);
  phase2<<<64, 64, 0, stream>>>(Mf, Sstart);
  phase3<<<50, 128, 0, stream>>>(x, a, Sstart, out);
}

// Round 3
// 198.237 us; speedup vs baseline: 3.6444x; 3.6444x over previous
//
#include <hip/hip_runtime.h>

// All-pole time-varying IIR via chunked affine-state decomposition.
// y[t] = K[t]*x[t] - sum_m A[t][m]*y[t-1-m], coeffs lin-interp per 80-sample frame.
// C=100 chunks of L=160 (2 frames). Phase1: 31 lane-runs/chunk build affine map (M_c, f_c).
// Phase2: per-batch scan s <- M_c s + f_c (depth-4 register prefetch).
// Phase3: exact re-run per chunk from known start state.
// Inner loops: (a) two-accumulator fold of coefficient interpolation
// (y = inp - acc_c0 - f*acc_dc), (b) 40-deep linear history window, 10-step
// static unroll eliminating the 30-mov/step shift.
// NOTE: every local-array index must be compile-time static (rule #20) —
// a single runtime-indexed access sends the whole array to scratch
// (round-2 regression: hh[29-role]=1 cost 6x).

#define Bb 64
#define Tt 16000
#define Nn 200
#define Pp 80
#define Mm 30
#define Dd 31
#define Cc 100
#define Ll 160

#define MF_FLOATS ((size_t)Bb * Cc * 31 * Mm)
#define SS_FLOATS ((size_t)Bb * Cc * Mm)

__device__ __forceinline__ void load_coeffs(const float* __restrict__ p0,
                                            const float* __restrict__ p1,
                                            float (&c0)[Mm], float (&dc)[Mm],
                                            float& K0, float& dK) {
  K0 = p0[0];
  dK = p1[0] - K0;
#pragma unroll
  for (int m = 0; m < Mm; ++m) {
    float v0 = p0[m + 1];
    c0[m] = v0;
    dc[m] = p1[m + 1] - v0;
  }
}

// ---------------- Phase 1: per-chunk transition matrices ----------------
__global__ __launch_bounds__(256, 3) void phase1(const float* __restrict__ x,
                                                 const float* __restrict__ a,
                                                 float* __restrict__ Mf) {
  const int tid = threadIdx.x;
  const int wave = tid >> 6, lane = tid & 63, half = lane >> 5, role = lane & 31;
  const int ch = ((blockIdx.x * 4 + wave) << 1) + half;
  const int b = ch / Cc, c = ch % Cc;

  float hh[40];
#pragma unroll
  for (int i = 0; i < 40; ++i) {
    // static select-init: hh[29-m]=1 for role==m, else 0. No runtime indices!
    hh[i] = (i < Mm && role == (29 - i)) ? 1.0f : 0.0f;
  }
  const float gmask = (role == 30) ? 1.f : 0.f;

  const float* abase = a + ((size_t)b * Nn + 2 * c) * Dd;
  float c0[Mm], dc[Mm], K0, dK;
  load_coeffs(abase, abase + Dd, c0, dc, K0, dK);  // frame 2c -> 2c+1 (always valid)

  const float* xp = x + (size_t)b * Tt + c * Ll;
  const float finc = 1.0f / Pp;
  float fbase = 0.f;

#pragma unroll 1
  for (int blk = 0; blk < 16; ++blk) {
    if (blk == 8) {
      const int n = 2 * c + 1;
      const float* p0 = a + ((size_t)b * Nn + n) * Dd;
      const float* p1 = (n + 1 < Nn) ? (p0 + Dd) : p0;
      load_coeffs(p0, p1, c0, dc, K0, dK);
      fbase = 0.f;
    }
    float xv[10];
    {
      const float2* x2 = reinterpret_cast<const float2*>(xp + blk * 10);
#pragma unroll
      for (int j = 0; j < 5; ++j) {
        float2 v = x2[j];
        xv[2 * j] = v.x;
        xv[2 * j + 1] = v.y;
      }
    }
#pragma unroll
    for (int k = 0; k < 10; ++k) {
      float a0 = 0.f, a1 = 0.f, d0 = 0.f, d1 = 0.f;
#pragma unroll
      for (int m = 0; m < Mm; m += 2) {
        float h0 = hh[29 + k - m];
        float h1 = hh[28 + k - m];
        a0 = fmaf(c0[m], h0, a0);
        d0 = fmaf(dc[m], h0, d0);
        a1 = fmaf(c0[m + 1], h1, a1);
        d1 = fmaf(dc[m + 1], h1, d1);
      }
      const float f = fmaf((float)k, finc, fbase);
      const float Kt = fmaf(dK, f, K0);
      const float inp = gmask * (Kt * xv[k]);
      const float y = fmaf(-f, d0 + d1, inp - (a0 + a1));
      hh[30 + k] = y;
    }
#pragma unroll
    for (int i = 0; i < 30; ++i) hh[i] = hh[i + 10];
    fbase += 10.0f * finc;  // 0.125 exact
  }

  if (role <= 30) {
    float* dst = Mf + ((size_t)ch * 31 + role) * Mm;
#pragma unroll
    for (int m = 0; m < Mm; ++m) dst[m] = hh[29 - m];
  }
}

// ---------------- Phase 2: sequential scan of chunk states ----------------
__device__ __forceinline__ void p2_load(const float* __restrict__ Mf, int ch, int lane,
                                        float (&R)[Dd]) {
  const float* nb = Mf + (size_t)ch * (31 * Mm);
  if (lane < Mm) {
#pragma unroll
    for (int j = 0; j < Dd; ++j) R[j] = nb[j * Mm + lane];  // R[j]=M[lane][j], R[30]=f[lane]
  }
}

__device__ __forceinline__ float p2_step(float s, const float (&R)[Dd]) {
  float a0 = R[Mm], a1 = 0.f;
#pragma unroll
  for (int j = 0; j < Mm; j += 2) {
    a0 = fmaf(R[j], __shfl(s, j, 64), a0);
    a1 = fmaf(R[j + 1], __shfl(s, j + 1, 64), a1);
  }
  return a0 + a1;
}

__global__ __launch_bounds__(64, 1) void phase2(const float* __restrict__ Mf,
                                                float* __restrict__ Sstart) {
  const int b = blockIdx.x, lane = threadIdx.x;
  const int chbase = b * Cc;
  float s = 0.f;
  float B0[Dd], B1[Dd], B2[Dd], B3[Dd];
  p2_load(Mf, chbase + 0, lane, B0);
  p2_load(Mf, chbase + 1, lane, B1);
  p2_load(Mf, chbase + 2, lane, B2);
  p2_load(Mf, chbase + 3, lane, B3);
#pragma unroll 1
  for (int c = 0; c < Cc; c += 4) {
    if (lane < Mm) Sstart[(size_t)(chbase + c) * Mm + lane] = s;
    s = p2_step(s, B0);
    if (c + 4 < Cc) p2_load(Mf, chbase + c + 4, lane, B0);
    if (lane < Mm) Sstart[(size_t)(chbase + c + 1) * Mm + lane] = s;
    s = p2_step(s, B1);
    if (c + 5 < Cc) p2_load(Mf, chbase + c + 5, lane, B1);
    if (lane < Mm) Sstart[(size_t)(chbase + c + 2) * Mm + lane] = s;
    s = p2_step(s, B2);
    if (c + 6 < Cc) p2_load(Mf, chbase + c + 6, lane, B2);
    if (lane < Mm) Sstart[(size_t)(chbase + c + 3) * Mm + lane] = s;
    s = p2_step(s, B3);
    if (c + 7 < Cc) p2_load(Mf, chbase + c + 7, lane, B3);
  }
}

// ---------------- Phase 3: exact re-run per chunk, one chunk per lane ----------------
__global__ __launch_bounds__(128, 1) void phase3(const float* __restrict__ x,
                                                 const float* __restrict__ a,
                                                 const float* __restrict__ Sstart,
                                                 float* __restrict__ out) {
  const int ch = blockIdx.x * 128 + threadIdx.x;  // 50 blocks * 128 = 6400 exactly
  const int b = ch / Cc, c = ch % Cc;

  float hh[40];
  const float* sp = Sstart + (size_t)ch * Mm;
#pragma unroll
  for (int m = 0; m < Mm; ++m) hh[29 - m] = sp[m];  // static (m is unroll var)
#pragma unroll
  for (int i = 30; i < 40; ++i) hh[i] = 0.f;

  const float* abase = a + ((size_t)b * Nn + 2 * c) * Dd;
  float c0[Mm], dc[Mm], K0, dK;
  load_coeffs(abase, abase + Dd, c0, dc, K0, dK);

  const float* xp = x + (size_t)b * Tt + c * Ll;
  float* yp = out + (size_t)b * Tt + c * Ll;
  const float finc = 1.0f / Pp;
  float fbase = 0.f;

#pragma unroll 1
  for (int blk = 0; blk < 16; ++blk) {
    if (blk == 8) {
      const int n = 2 * c + 1;
      const float* p0 = a + ((size_t)b * Nn + n) * Dd;
      const float* p1 = (n + 1 < Nn) ? (p0 + Dd) : p0;
      load_coeffs(p0, p1, c0, dc, K0, dK);
      fbase = 0.f;
    }
    float xv[10];
    {
      const float2* x2 = reinterpret_cast<const float2*>(xp + blk * 10);
#pragma unroll
      for (int j = 0; j < 5; ++j) {
        float2 v = x2[j];
        xv[2 * j] = v.x;
        xv[2 * j + 1] = v.y;
      }
    }
    float yv[10];
#pragma unroll
    for (int k = 0; k < 10; ++k) {
      float a0 = 0.f, a1 = 0.f, d0 = 0.f, d1 = 0.f;
#pragma unroll
      for (int m = 0; m < Mm; m += 2) {
        float h0 = hh[29 + k - m];
        float h1 = hh[28 + k - m];
        a0 = fmaf(c0[m], h0, a0);
        d0 = fmaf(dc[m], h0, d0);
        a1 = fmaf(c0[m + 1], h1, a1);
        d1 = fmaf(dc[m + 1], h1, d1);
      }
      const float f = fmaf((float)k, finc, fbase);
      const float Kt = fmaf(dK, f, K0);
      const float y = fmaf(-f, d0 + d1, fmaf(Kt, xv[k], -(a0 + a1)));
      yv[k] = y;
      hh[30 + k] = y;
    }
    {
      float2* y2 = reinterpret_cast<float2*>(yp + blk * 10);
#pragma unroll
      for (int j = 0; j < 5; ++j) y2[j] = make_float2(yv[2 * j], yv[2 * j + 1]);
    }
#pragma unroll
    for (int i = 0; i < 30; ++i) hh[i] = hh[i + 10];
    fbase += 10.0f * finc;
  }
}

// ---------------- Fallback: serial, one lane per batch ----------------
__global__ void naive_kernel(const float* __restrict__ x, const float* __restrict__ a,
                             float* __restrict__ out) {
  const int b = blockIdx.x * blockDim.x + threadIdx.x;
  if (b >= Bb) return;
  float h[Mm];
#pragma unroll
  for (int m = 0; m < Mm; ++m) h[m] = 0.f;
  for (int n = 0; n < Nn; ++n) {
    const float* p0 = a + ((size_t)b * Nn + n) * Dd;
    const float* p1 = a + ((size_t)b * Nn + min(n + 1, Nn - 1)) * Dd;
    float c0[Mm], dc[Mm];
#pragma unroll
    for (int m = 0; m < Mm; ++m) {
      float v0 = p0[m + 1];
      c0[m] = v0;
      dc[m] = p1[m + 1] - v0;
    }
    const float K0 = p0[0], dK = p1[0] - K0;
    const float* xp = x + (size_t)b * Tt + n * Pp;
    float* yp = out + (size_t)b * Tt + n * Pp;
    for (int i = 0; i < Pp; ++i) {
      const float f = (float)i * (1.0f / Pp);
      float acc = 0.f;
#pragma unroll
      for (int m = 0; m < Mm; ++m) acc = fmaf(fmaf(dc[m], f, c0[m]), h[m], acc);
      const float y = fmaf(fmaf(dK, f, K0), xp[i], -acc);
      yp[i] = y;
#pragma unroll
      for (int m = Mm - 1; m > 0; --m) h[m] = h[m - 1];
      h[0] = y;
    }
  }
}

extern "C" void kernel_launch(void* const* d_in, const int* in_sizes, int n_in,
                              void* d_out, int out_size, void* d_ws, size_t ws_size,
                              hipStream_t stream) {
  const float* x = (const float*)d_in[0];  // (64, 16000) f32
  const float* a = (const float*)d_in[1];  // (64, 200, 31) f32
  float* out = (float*)d_out;              // (64, 16000) f32

  const size_t need = (MF_FLOATS + SS_FLOATS) * sizeof(float);
  if (ws_size < need) {
    naive_kernel<<<1, 64, 0, stream>>>(x, a, out);
    return;
  }
  float* Mf = (float*)d_ws;
  float* Sstart = Mf + MF_FLOATS;

  phase1<<<800, 256, 0, stream>>>(x, a, Mf);
  phase2<<<64, 64, 0, stream>>>(Mf, Sstart);
  phase3<<<50, 128, 0, stream>>>(x, a, Sstart, out);
}